// Round 1
// baseline (133.969 us; speedup 1.0000x reference)
//
#include <hip/hip_runtime.h>
#include <cstdint>
#include <cstddef>

#define N_NODES 8192
#define F_IN 512
#define F_OUT 256
#define GAT_ALPHA 0.2f
#define THRESH 25.0f

__device__ __forceinline__ float lrelu(float x) { return x >= 0.f ? x : GAT_ALPHA * x; }

// ---------------- K1: H = X @ W  (8192x512 @ 512x256, fp32) ----------------
#define GBM 64
#define GBN 64
#define GBK 32
__global__ __launch_bounds__(256) void gemm_h(const float* __restrict__ X,
                                              const float* __restrict__ Wm,
                                              float* __restrict__ H) {
  __shared__ float As[GBM][GBK + 1];   // +1 pad: kills bank conflicts on column reads
  __shared__ float Bs[GBK][GBN];
  const int bm = blockIdx.x * GBM;
  const int bn = blockIdx.y * GBN;
  const int tid = threadIdx.x;
  const int tx = tid & 15, ty = tid >> 4;
  float acc[4][4] = {};

  for (int k0 = 0; k0 < F_IN; k0 += GBK) {
#pragma unroll
    for (int i = 0; i < 2; ++i) {
      const int idx = tid + i * 256;            // float4 index, 512 total per tile
      const int r = idx >> 3, c = (idx & 7) << 2;
      const float4 v = *reinterpret_cast<const float4*>(&X[(size_t)(bm + r) * F_IN + k0 + c]);
      As[r][c] = v.x; As[r][c + 1] = v.y; As[r][c + 2] = v.z; As[r][c + 3] = v.w;
      const int rb = idx >> 4, cb = (idx & 15) << 2;
      const float4 w = *reinterpret_cast<const float4*>(&Wm[(size_t)(k0 + rb) * F_OUT + bn + cb]);
      *reinterpret_cast<float4*>(&Bs[rb][cb]) = w;
    }
    __syncthreads();
#pragma unroll
    for (int kk = 0; kk < GBK; ++kk) {
      const float a0 = As[ty * 4 + 0][kk];
      const float a1 = As[ty * 4 + 1][kk];
      const float a2 = As[ty * 4 + 2][kk];
      const float a3 = As[ty * 4 + 3][kk];
      const float b0 = Bs[kk][tx * 4 + 0];
      const float b1 = Bs[kk][tx * 4 + 1];
      const float b2 = Bs[kk][tx * 4 + 2];
      const float b3 = Bs[kk][tx * 4 + 3];
      acc[0][0] += a0 * b0; acc[0][1] += a0 * b1; acc[0][2] += a0 * b2; acc[0][3] += a0 * b3;
      acc[1][0] += a1 * b0; acc[1][1] += a1 * b1; acc[1][2] += a1 * b2; acc[1][3] += a1 * b3;
      acc[2][0] += a2 * b0; acc[2][1] += a2 * b1; acc[2][2] += a2 * b2; acc[2][3] += a2 * b3;
      acc[3][0] += a3 * b0; acc[3][1] += a3 * b1; acc[3][2] += a3 * b2; acc[3][3] += a3 * b3;
    }
    __syncthreads();
  }
#pragma unroll
  for (int i = 0; i < 4; ++i)
#pragma unroll
    for (int j = 0; j < 4; ++j)
      H[(size_t)(bm + ty * 4 + i) * F_OUT + bn + tx * 4 + j] = acc[i][j];
}

// ---------------- K2: s1 = H@a1, s2 = H@a2 (one wave per row) ----------------
__global__ __launch_bounds__(256) void score_kernel(const float* __restrict__ H,
                                                    const float* __restrict__ a,
                                                    float* __restrict__ s1,
                                                    float* __restrict__ s2) {
  const int row = blockIdx.x * 4 + (threadIdx.x >> 6);
  const int lane = threadIdx.x & 63;
  float d1 = 0.f, d2 = 0.f;
#pragma unroll
  for (int c = lane; c < F_OUT; c += 64) {
    const float h = H[(size_t)row * F_OUT + c];
    d1 += h * a[c];
    d2 += h * a[F_OUT + c];
  }
#pragma unroll
  for (int off = 32; off; off >>= 1) {
    d1 += __shfl_down(d1, off);
    d2 += __shfl_down(d2, off);
  }
  if (lane == 0) { s1[row] = d1; s2[row] = d2; }
}

// ---------------- K3: fused masked softmax + sparse attention@H + elu ------
// One block (256 threads) per row. Pass 1: stream adj row once (coalesced),
// cache adjacency bytes + s2 in LDS, compute masked max m. Pass 2 (LDS only):
// survivors with e >= m - THRESH get exp'd and appended to a list; block then
// accumulates w * H[j][tid] (tid = output column). Dropped terms contribute
// < 4096*e^-25*|h| ~ 1e-5 -- far below the 1.64 absmax threshold.
__global__ __launch_bounds__(256) void attn_row(const int* __restrict__ adj,
                                                const float* __restrict__ s1v,
                                                const float* __restrict__ s2v,
                                                const float* __restrict__ H,
                                                float* __restrict__ out) {
  __shared__ float s2s[N_NODES];            // 32 KB
  __shared__ unsigned char adjb[N_NODES];   // 8 KB
  __shared__ int jlist[1024];               // 4 KB  (segment = 1024 cols -> cap safe)
  __shared__ float wlist[1024];             // 4 KB
  __shared__ float red[4];
  __shared__ int cnt;

  const int row = blockIdx.x;
  const int tid = threadIdx.x;
  const int lane = tid & 63;
  const int wid = tid >> 6;
  const float s1 = s1v[row];
  const int* __restrict__ arow = adj + (size_t)row * N_NODES;

  // ---- pass 1: load row, compute masked max ----
  float mloc = -INFINITY;
  for (int c0 = 0; c0 < N_NODES; c0 += 1024) {
    const int c = c0 + tid * 4;
    const int4 av = *reinterpret_cast<const int4*>(&arow[c]);
    const float4 sv = *reinterpret_cast<const float4*>(&s2v[c]);
    *reinterpret_cast<float4*>(&s2s[c]) = sv;
    uchar4 b;
    b.x = av.x > 0; b.y = av.y > 0; b.z = av.z > 0; b.w = av.w > 0;
    *reinterpret_cast<uchar4*>(&adjb[c]) = b;
    if (b.x) mloc = fmaxf(mloc, lrelu(s1 + sv.x));
    if (b.y) mloc = fmaxf(mloc, lrelu(s1 + sv.y));
    if (b.z) mloc = fmaxf(mloc, lrelu(s1 + sv.z));
    if (b.w) mloc = fmaxf(mloc, lrelu(s1 + sv.w));
  }
#pragma unroll
  for (int off = 32; off; off >>= 1) mloc = fmaxf(mloc, __shfl_down(mloc, off));
  if (lane == 0) red[wid] = mloc;
  __syncthreads();
  const float m = fmaxf(fmaxf(red[0], red[1]), fmaxf(red[2], red[3]));

  // ---- pass 2: survivors -> list -> accumulate ----
  float dloc = 0.f;
  float accv = 0.f;  // this thread owns output column `tid`
  for (int c0 = 0; c0 < N_NODES; c0 += 1024) {
    if (tid == 0) cnt = 0;
    __syncthreads();
    const int c = c0 + tid * 4;
    const uchar4 b = *reinterpret_cast<const uchar4*>(&adjb[c]);
    const float4 sv = *reinterpret_cast<const float4*>(&s2s[c]);
#pragma unroll
    for (int k = 0; k < 4; ++k) {
      const unsigned char bk = (&b.x)[k];
      const float s2k = (&sv.x)[k];
      if (bk) {
        const float e = lrelu(s1 + s2k);
        if (e >= m - THRESH) {
          const float w = expf(e - m);
          dloc += w;
          const int p = atomicAdd(&cnt, 1);
          jlist[p] = c + k;
          wlist[p] = w;
        }
      }
    }
    __syncthreads();
    const int n = cnt;
    for (int idx = 0; idx < n; ++idx) {
      accv += wlist[idx] * H[(size_t)jlist[idx] * F_OUT + tid];
    }
    __syncthreads();
  }

  // ---- reduce denominator, write elu(acc/d) ----
#pragma unroll
  for (int off = 32; off; off >>= 1) dloc += __shfl_down(dloc, off);
  if (lane == 0) red[wid] = dloc;
  __syncthreads();
  const float d = red[0] + red[1] + red[2] + red[3];
  const float v = accv / d;
  out[(size_t)row * F_OUT + tid] = v > 0.f ? v : expm1f(v);
}

extern "C" void kernel_launch(void* const* d_in, const int* in_sizes, int n_in,
                              void* d_out, int out_size, void* d_ws, size_t ws_size,
                              hipStream_t stream) {
  const float* x = (const float*)d_in[0];
  const int* adj = (const int*)d_in[1];
  const float* Wm = (const float*)d_in[2];
  const float* a = (const float*)d_in[3];
  float* out = (float*)d_out;

  char* ws = (char*)d_ws;
  float* H = (float*)ws;                                   // 8192*256*4 = 8 MB
  float* s1 = (float*)(ws + (size_t)N_NODES * F_OUT * 4);  // 32 KB
  float* s2 = s1 + N_NODES;                                // 32 KB

  gemm_h<<<dim3(N_NODES / GBM, F_OUT / GBN), 256, 0, stream>>>(x, Wm, H);
  score_kernel<<<N_NODES / 4, 256, 0, stream>>>(H, a, s1, s2);
  attn_row<<<N_NODES, 256, 0, stream>>>(adj, s1, s2, H, out);
}